// Round 6
// baseline (266.285 us; speedup 1.0000x reference)
//
#include <hip/hip_runtime.h>
#include <cstdint>
#include <cstddef>

typedef unsigned int u32;
typedef unsigned long long u64;

#define NBATCH 16
#define NA 9
#define HF 160
#define WF 160
#define HWC (HF*WF)          // 25600
#define NPB (NA*HWC)         // 230400 anchors per image
#define PRE_N 6000
#define POST_N 300
#define SEL_CAP 8192
#define NBIN 2048            // fallback radix bins
#define UNI_BINS 2048        // uniform score bins (2^11; s*2048 and q/2048 are exact fp32)
#define BQ 128               // NMS batch size

// Anchor constants derived exactly from generate_anchors(16,[0.5,1,2],[8,16,32]):
// all anchors have center (8,8) at cell (0,0); only w/h differ.
__constant__ float c_AW[9] = {184.f,368.f,736.f,128.f,256.f,512.f,88.f,176.f,352.f};
__constant__ float c_AH[9] = {96.f,192.f,384.f,128.f,256.f,512.f,176.f,352.f,704.f};

__device__ __forceinline__ void box_from_deltas(
    const float* __restrict__ bd, int b, int a, int pos,
    float imH, float imW, float ms,
    float& x1, float& y1, float& x2, float& y2, bool& keep)
{
  int y = pos / WF;
  int x = pos - y * WF;
  size_t base = ((size_t)(b * 4 * NA) + 4 * a) * HWC + (size_t)pos;
  float d0 = bd[base];
  float d1 = bd[base + HWC];
  float d2 = bd[base + 2 * HWC];
  float d3 = bd[base + 3 * HWC];
  float aw = c_AW[a], ah = c_AH[a];
  float acx = (float)x * 16.0f + 8.0f;
  float acy = (float)y * 16.0f + 8.0f;
  float pcx = d0 * aw + acx;
  float pcy = d1 * ah + acy;
  float pw  = expf(d2) * aw;
  float ph  = expf(d3) * ah;
  x1 = fminf(fmaxf(pcx - 0.5f * pw, 0.0f), imW - 1.0f);
  y1 = fminf(fmaxf(pcy - 0.5f * ph, 0.0f), imH - 1.0f);
  x2 = fminf(fmaxf(pcx + 0.5f * pw, 0.0f), imW - 1.0f);
  y2 = fminf(fmaxf(pcy + 0.5f * ph, 0.0f), imH - 1.0f);
  keep = ((x2 - x1 + 1.0f) >= ms) && ((y2 - y1 + 1.0f) >= ms);
}

__device__ __forceinline__ u32 desc_enc(float s) {
  u32 su = __float_as_uint(s);
  u32 asc = (su & 0x80000000u) ? ~su : (su | 0x80000000u);
  return ~asc;
}

// Exact divide-free IoU>0.7 test: fmaf sign is exact; fall back to the IEEE
// divide (same operand order as reference) only in the borderline band.
__device__ __forceinline__ bool iou_gt(float inter, float uni) {
  float ss = fmaf(0.7f, uni, -inter);
  if (fabsf(ss) <= uni * 1e-6f) return (inter / uni > 0.7f);
  return ss < 0.0f;
}

// Score codes (u32, descending order-flip) + single-pass uniform-bin histogram.
// Tie-break index i = pos*9 + a is recomputed downstream from the linear slot,
// so only 4B/anchor is written (was 8B).
__global__ void __launch_bounds__(256) k_scores_hist(
    const float* __restrict__ sm, const float* __restrict__ bd,
    const float* __restrict__ info, u32* __restrict__ hkeys, u32* __restrict__ hist) {
  __shared__ u32 lh[UNI_BINS];
  int img = blockIdx.x / 60;
  int slice = blockIdx.x % 60;
  int tid = threadIdx.x;
  for (int i = tid; i < UNI_BINS; i += 256) lh[i] = 0;
  __syncthreads();
  float imH = info[img*3+0], imW = info[img*3+1], ms = 16.0f * info[img*3+2];
  for (int j = 0; j < 15; j++) {
    int t = slice * 3840 + j * 256 + tid;
    int a = t / HWC;
    int pos = t - a * HWC;
    float s = sm[((size_t)(img * 2 * NA) + NA + a) * HWC + (size_t)pos];
    float x1, y1, x2, y2; bool keep;
    box_from_deltas(bd, img, a, pos, imH, imW, ms, x1, y1, x2, y2, keep);
    if (!keep) s = __uint_as_float(0xFF800000u);  // -inf
    hkeys[(size_t)img * NPB + t] = desc_enc(s);
    int q = (int)floorf(s * (float)UNI_BINS);
    q = q < 0 ? 0 : (q > UNI_BINS - 1 ? UNI_BINS - 1 : q);
    atomicAdd(&lh[(UNI_BINS - 1) - q], 1u);
  }
  __syncthreads();
  u32* gh = hist + img * UNI_BINS;
  for (int i = tid; i < UNI_BINS; i += 256) { u32 v = lh[i]; if (v) atomicAdd(&gh[i], v); }
}

// Fused select + compact + box decode. Every block redundantly computes the
// threshold from the (tiny, L2-hot) hist — deterministic, identical across
// blocks — then compacts its 3840-key slice with one atomicAdd per block.
// Sort element: [desc:32 (bits 62..31) | anchoridx:18 (30..13) | slot:13 (12..0)].
__global__ void __launch_bounds__(256) k_compactsel(
    const u32* __restrict__ hkeys, const u32* __restrict__ hist,
    u32* __restrict__ selcnt, u64* __restrict__ sel,
    const float* __restrict__ bd, const float* __restrict__ info,
    float4* __restrict__ boxsel) {
  int img = blockIdx.y;
  int tid = threadIdx.x;
  __shared__ u32 sc[256];
  __shared__ u32 lh[NBIN];
  __shared__ u64 sh_thresh;
  __shared__ int sh_state;
  __shared__ u64 sh_prefix;
  __shared__ u32 sh_kth;
  __shared__ u32 sbase;
  // ---- select: fast path from uniform hist ----
  {
    const u32* gh = hist + img * UNI_BINS;
    u32 loc[8]; u32 tot = 0;
    for (int j = 0; j < 8; j++) { loc[j] = gh[tid * 8 + j]; tot += loc[j]; }
    if (tid == 0) { sh_state = 0; sh_prefix = 0; sh_kth = PRE_N; }
    sc[tid] = tot;
    __syncthreads();
    for (int off = 1; off < 256; off <<= 1) {
      u32 v = sc[tid]; u32 a = (tid >= off) ? sc[tid - off] : 0u;
      __syncthreads(); sc[tid] = v + a; __syncthreads();
    }
    u32 incl = sc[tid], excl = incl - tot;
    if (PRE_N > excl && PRE_N <= incl) {
      u32 run = excl;
      for (int j = 0; j < 8; j++) {
        run += loc[j];
        if (run >= PRE_N) {
          int b = tid * 8 + j;
          if (b < UNI_BINS - 1 && run <= SEL_CAP) {
            float sb = (float)(UNI_BINS - 1 - b) * (1.0f / (float)UNI_BINS);
            sh_thresh = ((u64)desc_enc(sb) << 32) | 0xFFFFFFFFull;
            sh_state = 1;
          }
          break;
        }
      }
    }
    __syncthreads();
  }
  // ---- exact radix fallback (pathological ties only; redundant per block) ----
  if (!sh_state) {
    const u32* hk = hkeys + (size_t)img * NPB;
    const int shifts[6] = {53, 42, 31, 20, 9, 0};
    const int widths[6] = {11, 11, 11, 11, 11, 9};
    for (int p = 0; p < 6; p++) {
      if (sh_state) break;
      for (int i = tid; i < NBIN; i += 256) lh[i] = 0;
      __syncthreads();
      u64 prefix = sh_prefix; u32 kth = sh_kth;
      int shift = shifts[p], width = widths[p];
      u32 nb = 1u << width;
      int hs = shift + width;
      for (int i = tid; i < NPB; i += 256) {
        int a = i / HWC; int pos = i - a * HWC;
        u64 key = ((u64)hk[i] << 32) | (u64)(u32)(pos * NA + a);
        bool m = (p == 0) || ((key >> hs) == prefix);
        if (m) atomicAdd(&lh[(u32)(key >> shift) & (nb - 1u)], 1u);
      }
      __syncthreads();
      u32 l2[8]; u32 t2 = 0;
      for (int j = 0; j < 8; j++) {
        u32 b = (u32)(tid * 8 + j);
        u32 v = (b < nb) ? lh[b] : 0u;
        l2[j] = v; t2 += v;
      }
      sc[tid] = t2; __syncthreads();
      for (int off = 1; off < 256; off <<= 1) {
        u32 v = sc[tid]; u32 a = (tid >= off) ? sc[tid - off] : 0u;
        __syncthreads(); sc[tid] = v + a; __syncthreads();
      }
      u32 incl2 = sc[tid], excl2 = incl2 - t2;
      if (kth > excl2 && kth <= incl2) {
        u32 run = excl2;
        for (int j = 0; j < 8; j++) {
          run += l2[j];
          if (run >= kth) {
            u32 bin = (u32)(tid * 8 + j);
            u32 below = run - l2[j];
            u32 cnt = l2[j];
            u32 knew = kth - below;
            u64 pfull = (prefix << width) | (u64)bin;
            u32 M = (u32)PRE_N - knew + cnt;
            if (M <= SEL_CAP) {
              u64 lowmask = (shift > 0) ? ((1ULL << shift) - 1ULL) : 0ULL;
              sh_thresh = (pfull << shift) | lowmask;
              sh_state = 1;
            } else {
              sh_prefix = pfull; sh_kth = knew;
            }
            break;
          }
        }
      }
      __syncthreads();
    }
  }
  u64 T = sh_thresh;
  // ---- compact sweep ----
  const u32* hp = hkeys + (size_t)img * NPB + (size_t)blockIdx.x * 3840;
  u32 mycnt = 0;
  #pragma unroll
  for (int j = 0; j < 15; j++) {
    int t = blockIdx.x * 3840 + j * 256 + tid;
    int a = t / HWC; int pos = t - a * HWC;
    u64 key = ((u64)hp[j * 256 + tid] << 32) | (u64)(u32)(pos * NA + a);
    if (key <= T) mycnt++;
  }
  sc[tid] = mycnt;
  __syncthreads();
  for (int off = 1; off < 256; off <<= 1) {
    u32 v = sc[tid];
    u32 add = (tid >= off) ? sc[tid - off] : 0u;
    __syncthreads();
    sc[tid] = v + add;
    __syncthreads();
  }
  if (tid == 255 && sc[255] > 0) sbase = atomicAdd(&selcnt[img], sc[255]);
  __syncthreads();
  if (mycnt == 0) return;
  u32 myoff = sbase + sc[tid] - mycnt;
  u64* sp = sel + (size_t)img * SEL_CAP;
  float4* bp = boxsel + (size_t)img * SEL_CAP;
  float imH = info[img*3+0], imW = info[img*3+1], ms = 16.0f * info[img*3+2];
  u32 c = 0;
  #pragma unroll
  for (int j = 0; j < 15; j++) {
    int t = blockIdx.x * 3840 + j * 256 + tid;
    int a = t / HWC; int pos = t - a * HWC;
    u32 idx = (u32)(pos * NA + a);
    u32 dsc = hp[j * 256 + tid];
    u64 key = ((u64)dsc << 32) | (u64)idx;
    if (key <= T) {
      u32 p = myoff + c;
      if (p < SEL_CAP) {
        sp[p] = ((u64)dsc << 31) | ((u64)idx << 13) | (u64)p;
        float x1, y1, x2, y2; bool keep;
        box_from_deltas(bd, img, a, pos, imH, imW, ms, x1, y1, x2, y2, keep);
        bp[p] = make_float4(x1, y1, x2, y2);
      }
      c++;
    }
  }
}

// Stage 1: sort each 1024-key chunk ascending in LDS (8 chunks/image x 16 images
// = 128 blocks -> full-chip parallelism for the 55 bitonic phases).
__global__ void __launch_bounds__(256) k_sort1(u64* __restrict__ sel, const u32* __restrict__ selcnt) {
  __shared__ u64 s[1024];
  int img = blockIdx.y, c = blockIdx.x, tid = threadIdx.x;
  u32 cnt = selcnt[img]; if (cnt > SEL_CAP) cnt = SEL_CAP;
  u64* sp = sel + (size_t)img * SEL_CAP + (size_t)c * 1024;
  int gbase = c * 1024;
  for (int i = tid; i < 1024; i += 256) s[i] = ((u32)(gbase + i) < cnt) ? sp[i] : ~0ULL;
  __syncthreads();
  for (int k = 2; k <= 1024; k <<= 1) {
    for (int j = k >> 1; j > 0; j >>= 1) {
      for (int i = tid; i < 1024; i += 256) {
        int p = i ^ j;
        if (p > i) {
          u64 a = s[i], b = s[p];
          bool up = ((i & k) == 0);
          if (up ? (a > b) : (a < b)) { s[i] = b; s[p] = a; }
        }
      }
      __syncthreads();
    }
  }
  for (int i = tid; i < 1024; i += 256) sp[i] = s[i];
}

// Fused merge + NMS. Merge-path (3 levels, 6 barriers) establishes exact order;
// slots stay in LDS; candidate boxes gathered from boxsel (L2). NMS: batches of
// 128, within-batch 128x128 pair masks (2xu64 rows in wave-0 registers), serial
// chain = ffs + 2 shfls + ands; prefetch + zeroing overlap the serial phase.
__global__ void __launch_bounds__(1024) k_sortnms(
    const u64* __restrict__ sel, const float4* __restrict__ boxsel,
    float* __restrict__ out) {
  union LdsU {
    u64 s[SEL_CAP];                      // 64 KiB (merge phase)
    struct {
      u32 sl[PRE_N];                     // rank -> slot
      float4 kbox[POST_N];
      float karea[POST_N];
      u64 kcodeW[40];                    // packed u8 area codes of kept
      float4 cb[2][BQ];
      float car[2][BQ];
      unsigned char ccode[2][BQ];
      u64 winm[2][BQ][2];                // within-batch suppression rows
      u64 supw[2][16];                   // per-wave vs-kept ballots
    } n;
  };
  __shared__ LdsU U;
  __shared__ int sh_nv, sh_nkept;
  int img = blockIdx.x;
  int tid = threadIdx.x;
  int lane = tid & 63;
  int wv = tid >> 6;
  const u64* sp = sel + (size_t)img * SEL_CAP;
  for (int i = tid; i < SEL_CAP; i += 1024) U.s[i] = sp[i];
  if (tid == 0) { sh_nv = PRE_N; sh_nkept = 0; }
  __syncthreads();
  // ---- merge-path: 1024 -> 2048 -> 4096 -> 8192 ----
  int d0 = tid * 8;
  for (int Lw = 1024; Lw < SEL_CAP; Lw <<= 1) {
    int pairBase = d0 & ~(2 * Lw - 1);
    int d = d0 - pairBase;
    const u64* A = U.s + pairBase;
    const u64* B = U.s + pairBase + Lw;
    int lo = d - Lw; if (lo < 0) lo = 0;
    int hi = (d < Lw) ? d : Lw;
    while (lo < hi) {
      int mid = (lo + hi) >> 1;
      if (A[mid] <= B[d - 1 - mid]) lo = mid + 1; else hi = mid;
    }
    int ia = lo, ib = d - lo;
    u64 o[8];
    #pragma unroll
    for (int k = 0; k < 8; k++) {
      bool ta = (ib >= Lw) || (ia < Lw && A[ia] <= B[ib]);
      o[k] = ta ? A[ia++] : B[ib++];
    }
    __syncthreads();
    #pragma unroll
    for (int k = 0; k < 8; k++) U.s[d0 + k] = o[k];
    __syncthreads();
  }
  // ---- extract rank->slot into regs, then repurpose LDS for NMS ----
  u32 myslot[6]; bool myval[6];
  #pragma unroll
  for (int k = 0; k < 6; k++) {
    int r = tid + k * 1024;
    myval[k] = false; myslot[k] = 0;
    if (r < PRE_N) {
      u64 key = U.s[r];
      u32 dsc = (u32)(key >> 31);
      bool valid = dsc < 0xFF800000u;     // score > -inf (padding ~0 -> invalid)
      myslot[k] = (u32)(key & 0x1FFFu);
      myval[k] = valid;
      if (!valid) atomicMin(&sh_nv, r);
    }
  }
  __syncthreads();
  #pragma unroll
  for (int k = 0; k < 6; k++) {
    int r = tid + k * 1024;
    if (r < PRE_N) U.n.sl[r] = myval[k] ? myslot[k] : 0u;
  }
  __syncthreads();
  int nvalid = sh_nv;
  const float4* bp = boxsel + (size_t)img * SEL_CAP;
  // ---- initial batch load + state zeroing ----
  if (wv < 2) {
    int i = wv * 64 + lane;
    float4 c4 = (i < nvalid) ? bp[U.n.sl[i]] : make_float4(0.f, 0.f, 0.f, 0.f);
    U.n.cb[0][i] = c4;
    float A = (c4.z - c4.x + 1.0f) * (c4.w - c4.y + 1.0f);
    U.n.car[0][i] = A;
    U.n.ccode[0][i] = (unsigned char)(int)rintf(8.0f * log2f(A));
  } else if (wv == 2) {
    U.n.winm[0][lane][0] = 0; U.n.winm[0][lane][1] = 0;
  } else if (wv == 3) {
    U.n.winm[0][64 + lane][0] = 0; U.n.winm[0][64 + lane][1] = 0;
  } else if (wv == 4) {
    if (lane < 16) U.n.supw[0][lane] = 0;
  }
  __syncthreads();
  // ---- batched-lazy greedy NMS ----
  int pb = 0;
  for (int base = 0; base < nvalid; base += BQ, pb ^= 1) {
    int nk = sh_nkept;
    if (nk >= POST_N) break;
    int bn = nvalid - base; if (bn > BQ) bn = BQ;
    int c = tid & (BQ - 1);
    int g = tid >> 7;                    // 8 kept-scan groups
    bool inb = c < bn;
    bool sup = !inb;
    u64 wlo = 0, whi = 0;
    if (inb) {
      float4 C = U.n.cb[pb][c];
      float A0 = U.n.car[pb][c];
      int myc = (int)U.n.ccode[pb][c];
      int nw = (nk + 7) >> 3;
      for (int jw = g; jw < nw && !sup; jw += 8) {
        u64 w = U.n.kcodeW[jw];
        int jbase = jw << 3;
        int jm = nk - jbase; if (jm > 8) jm = 8;
        for (int k = 0; k < jm; k++) {
          int d = (int)((w >> (k * 8)) & 0xFFu) - myc;
          if (d > 5 || d < -5) continue;          // conservative area-ratio gate
          int j = jbase + k;
          float4 K = U.n.kbox[j];
          float xx1 = fmaxf(K.x, C.x);
          float yy1 = fmaxf(K.y, C.y);
          float xx2 = fminf(K.z, C.z);
          float yy2 = fminf(K.w, C.w);
          float iw = fmaxf(0.0f, xx2 - xx1 + 1.0f);
          float ih = fmaxf(0.0f, yy2 - yy1 + 1.0f);
          float inter = iw * ih;
          float uni = (U.n.karea[j] + A0) - inter;   // kept area first (ref order)
          if (iou_gt(inter, uni)) { sup = true; break; }
        }
      }
      for (int j = c + 1 + g; j < bn; j += 8) {
        float Aj = U.n.car[pb][j];
        if (Aj <= 0.6999f * A0 || A0 <= 0.6999f * Aj) continue;
        float4 J = U.n.cb[pb][j];
        float xx1 = fmaxf(C.x, J.x);
        float yy1 = fmaxf(C.y, J.y);
        float xx2 = fminf(C.z, J.z);
        float yy2 = fminf(C.w, J.w);
        float iw = fmaxf(0.0f, xx2 - xx1 + 1.0f);
        float ih = fmaxf(0.0f, yy2 - yy1 + 1.0f);
        float inter = iw * ih;
        float uni = (A0 + Aj) - inter;               // earlier area first
        if (iou_gt(inter, uni)) {
          if (j < 64) wlo |= 1ULL << j; else whi |= 1ULL << (j - 64);
        }
      }
    }
    u64 bm = __ballot(sup);               // wave wv covers c = (wv&1)*64 + lane
    if (lane == 0) U.n.supw[pb][wv] = bm;
    if (wlo) atomicOr(&U.n.winm[pb][c][0], wlo);
    if (whi) atomicOr(&U.n.winm[pb][c][1], whi);
    __syncthreads();
    if (wv == 0) {
      u64 a = (lane < 16) ? U.n.supw[pb][lane] : 0ULL;
      a |= __shfl_xor(a, 2); a |= __shfl_xor(a, 4); a |= __shfl_xor(a, 8);
      u64 so_lo = __shfl(a, 0);
      u64 so_hi = __shfl(a, 1);
      u64 rl0 = U.n.winm[pb][lane][0],      rl1 = U.n.winm[pb][lane][1];
      u64 rh0 = U.n.winm[pb][64 + lane][0], rh1 = U.n.winm[pb][64 + lane][1];
      u64 vlo = (bn >= 64) ? ~0ULL : ((1ULL << bn) - 1ULL);
      u64 vhi = (bn <= 64) ? 0ULL : ((bn >= BQ) ? ~0ULL : ((1ULL << (bn - 64)) - 1ULL));
      u64 live_lo = vlo & ~so_lo, live_hi = vhi & ~so_hi;
      u64 km_lo = 0, km_hi = 0;
      int cnt = nk;
      while ((live_lo | live_hi) && cnt < POST_N) {
        u64 m0, m1;
        if (live_lo) {
          int cc = __ffsll((long long)live_lo) - 1;
          km_lo |= 1ULL << cc;
          m0 = __shfl(rl0, cc); m1 = __shfl(rl1, cc);
          live_lo &= ~(1ULL << cc);
        } else {
          int cc = __ffsll((long long)live_hi) - 1;
          km_hi |= 1ULL << cc;
          m0 = __shfl(rh0, cc); m1 = __shfl(rh1, cc);
          live_hi &= ~(1ULL << cc);
        }
        cnt++;
        live_lo &= ~m0; live_hi &= ~m1;
      }
      int nlo = __popcll(km_lo);
      if ((km_lo >> lane) & 1ULL) {
        int rank = nk + (int)__popcll(km_lo & ((1ULL << lane) - 1ULL));
        float4 C = U.n.cb[pb][lane];
        U.n.kbox[rank] = C;
        U.n.karea[rank] = U.n.car[pb][lane];
        ((unsigned char*)U.n.kcodeW)[rank] = U.n.ccode[pb][lane];
        float* o = out + ((size_t)img * POST_N + rank) * 5;
        o[0] = (float)img; o[1] = C.x; o[2] = C.y; o[3] = C.z; o[4] = C.w;
      }
      if ((km_hi >> lane) & 1ULL) {
        int rank = nk + nlo + (int)__popcll(km_hi & ((1ULL << lane) - 1ULL));
        float4 C = U.n.cb[pb][64 + lane];
        U.n.kbox[rank] = C;
        U.n.karea[rank] = U.n.car[pb][64 + lane];
        ((unsigned char*)U.n.kcodeW)[rank] = U.n.ccode[pb][64 + lane];
        float* o = out + ((size_t)img * POST_N + rank) * 5;
        o[0] = (float)img; o[1] = C.x; o[2] = C.y; o[3] = C.z; o[4] = C.w;
      }
      if (lane == 0) sh_nkept = cnt;
    } else if (wv == 1 || wv == 2) {
      if (base + BQ < nvalid) {
        int i = (wv - 1) * 64 + lane;
        int gi = base + BQ + i;
        float4 c4 = (gi < nvalid) ? bp[U.n.sl[gi]] : make_float4(0.f, 0.f, 0.f, 0.f);
        U.n.cb[pb ^ 1][i] = c4;
        float A = (c4.z - c4.x + 1.0f) * (c4.w - c4.y + 1.0f);
        U.n.car[pb ^ 1][i] = A;
        U.n.ccode[pb ^ 1][i] = (unsigned char)(int)rintf(8.0f * log2f(A));
      }
    } else if (wv == 3) {
      U.n.winm[pb ^ 1][lane][0] = 0; U.n.winm[pb ^ 1][lane][1] = 0;
    } else if (wv == 4) {
      U.n.winm[pb ^ 1][64 + lane][0] = 0; U.n.winm[pb ^ 1][64 + lane][1] = 0;
    } else if (wv == 5) {
      if (lane < 16) U.n.supw[pb ^ 1][lane] = 0;
    }
    __syncthreads();
  }
  int fk = sh_nkept;
  for (int r = fk + tid; r < POST_N; r += 1024) {
    float* o = out + ((size_t)img * POST_N + r) * 5;
    o[0] = (float)img; o[1] = 0.f; o[2] = 0.f; o[3] = 0.f; o[4] = 0.f;
  }
}

extern "C" void kernel_launch(void* const* d_in, const int* in_sizes, int n_in,
                              void* d_out, int out_size, void* d_ws, size_t ws_size,
                              hipStream_t stream) {
  const float* sm   = (const float*)d_in[0];
  const float* bd   = (const float*)d_in[1];
  const float* info = (const float*)d_in[2];
  float* out = (float*)d_out;
  char* ws = (char*)d_ws;

  size_t off = 0;
  auto alloc = [&](size_t bytes) { size_t o = off; off += (bytes + 255) & ~(size_t)255; return o; };
  u32* hkeys    = (u32*)(ws + alloc((size_t)NBATCH * NPB * 4));        // 14.7 MB
  size_t off_hist = alloc((size_t)NBATCH * UNI_BINS * 4);              // 128 KB
  u32* hist     = (u32*)(ws + off_hist);
  u32* selcnt   = (u32*)(ws + alloc(NBATCH * 4));                      // adjacent to hist
  size_t zero_end = off;
  u64* sel      = (u64*)(ws + alloc((size_t)NBATCH * SEL_CAP * 8));    // 1 MB
  float4* boxsel= (float4*)(ws + alloc((size_t)NBATCH * SEL_CAP * 16));// 2 MB
  (void)ws_size; (void)in_sizes; (void)n_in; (void)out_size;

  hipMemsetAsync(ws + off_hist, 0, zero_end - off_hist, stream);       // hist + selcnt
  hipLaunchKernelGGL(k_scores_hist, dim3(960), dim3(256), 0, stream, sm, bd, info, hkeys, hist);
  hipLaunchKernelGGL(k_compactsel, dim3(60, 16), dim3(256), 0, stream,
                     hkeys, hist, selcnt, sel, bd, info, boxsel);
  hipLaunchKernelGGL(k_sort1, dim3(8, 16), dim3(256), 0, stream, sel, selcnt);
  hipLaunchKernelGGL(k_sortnms, dim3(16), dim3(1024), 0, stream, sel, boxsel, out);
}